// Round 5
// baseline (389.792 us; speedup 1.0000x reference)
//
#include <hip/hip_runtime.h>

// db4 filters as compile-time constants (immediates / s_mov, no K$ loads)
__device__ constexpr float DEC_LO[8] = {
    -0.010597401784997278f, 0.032883011666982945f, 0.030841381835986965f,
    -0.18703481171888114f, -0.02798376941698385f, 0.6308807679295904f,
    0.7148465705525415f, 0.23037781330885523f};
__device__ constexpr float DEC_HI[8] = {
    -0.23037781330885523f, 0.7148465705525415f, -0.6308807679295904f,
    -0.02798376941698385f, 0.18703481171888114f, 0.030841381835986965f,
    -0.032883011666982945f, -0.010597401784997278f};
__device__ constexpr float REC_LO[8] = {
    0.23037781330885523f, 0.7148465705525415f, 0.6308807679295904f,
    -0.02798376941698385f, -0.18703481171888114f, 0.030841381835986965f,
    0.032883011666982945f, -0.010597401784997278f};
__device__ constexpr float REC_HI[8] = {
    -0.010597401784997278f, -0.032883011666982945f, 0.030841381835986965f,
    0.18703481171888114f, -0.02798376941698385f, -0.6308807679295904f,
    0.7148465705525415f, -0.23037781330885523f};

__device__ __forceinline__ float soft_enh(float v, float th) {
    float e = 1.5f * v;
    float a = fabsf(e) - th;
    return a > 0.0f ? copysignf(a, e) : 0.0f;
}

#define TB 32
#define TO 64
#define RAWL_ROWS 70

// ===================== Kernel A: fused 2D DWT =====================
// Input  X[a][b] (b contiguous). Row-pass filters along b, col-pass along a.
// Output bands stored TRANSPOSED: band[c][d] with c = b-freq, d = a-freq.
// (Consumers filter along d first -> their loads become contiguous.)
// Stores: thread owns (c=jw, 4 consecutive d=jh) -> 8B-aligned float2 pairs.
__global__ __launch_bounds__(256, 4) void fused_dwt2_k(
    const float* __restrict__ x, int S, int Nc, int tiles,
    float* __restrict__ aa, float* __restrict__ da,
    float* __restrict__ ad, float* __restrict__ dd,
    unsigned* __restrict__ mx_da, unsigned* __restrict__ mx_ad,
    unsigned* __restrict__ mx_dd)
{
    int b = blockIdx.x;
    int tx = b % tiles, ty = (b / tiles) % tiles, m = b / (tiles * tiles);
    int jh0 = ty * TB, jw0 = tx * TB;
    int r0 = 2 * jh0 - 6, c0 = 2 * jw0 - 6;
    const float* xm = x + (size_t)m * S * S;

    __shared__ float rawL[RAWL_ROWS * 64];   // 17,920 B
    __shared__ float rawR[72 * 8];           //  2,304 B
    __shared__ float RB[70][68];             // 19,040 B

    int tid = threadIdx.x;
    int wv = tid >> 6, ln = tid & 63;

    auto refl = [S](int p) {
        p = p < 0 ? -1 - p : p;
        return p >= S ? 2 * S - 1 - p : p;
    };

    // --- async stage, rawL: one 64-lane DMA per row
    int pcL = refl(c0 + ln);                 // per-lane, once
    for (int w = wv; w < RAWL_ROWS; w += 4) {
        int pr = refl(r0 + w);               // wave-uniform (SALU)
        const float* g = xm + (size_t)pr * S + pcL;
#if defined(__has_builtin) && __has_builtin(__builtin_amdgcn_global_load_lds)
        __builtin_amdgcn_global_load_lds(
            (const __attribute__((address_space(1))) void*)g,
            (__attribute__((address_space(3))) void*)(&rawL[w << 6]),
            4, 0, 0);
#else
        rawL[(w << 6) + ln] = *g;
#endif
    }
    // --- async stage, rawR: 9 chunks, r = 8w + (ln>>3), c = 64 + (ln&7)
    int pcR = refl(c0 + 64 + (ln & 7));      // per-lane, once
    int rsub = ln >> 3;
    for (int w = wv; w < 9; w += 4) {
        int r = (w << 3) + rsub;
        if (r > 69) r = 69;                  // dup read; dest stays in pad rows
        int pr = refl(r0 + r);
        const float* g = xm + (size_t)pr * S + pcR;
#if defined(__has_builtin) && __has_builtin(__builtin_amdgcn_global_load_lds)
        __builtin_amdgcn_global_load_lds(
            (const __attribute__((address_space(1))) void*)g,
            (__attribute__((address_space(3))) void*)(&rawR[w << 6]),
            4, 0, 0);
#else
        rawR[(w << 6) + ln] = *g;
#endif
    }
    __syncthreads();   // single vmcnt drain for all staging DMA

    // --- row dwt from LDS: 560 tasks (row r, quad q), 4 outputs each
    for (int e = tid; e < 560; e += 256) {
        int r = e >> 3, q = e & 7;
        float f[16];
        if (q < 7) {
            const float* base = &rawL[(r << 6) + (q << 3)];
            float4 A = *reinterpret_cast<const float4*>(base);
            float4 B = *reinterpret_cast<const float4*>(base + 4);
            float4 C = *reinterpret_cast<const float4*>(base + 8);
            float4 D = *reinterpret_cast<const float4*>(base + 12);
            f[0] = A.x; f[1] = A.y; f[2] = A.z; f[3] = A.w;
            f[4] = B.x; f[5] = B.y; f[6] = B.z; f[7] = B.w;
            f[8] = C.x; f[9] = C.y; f[10] = C.z; f[11] = C.w;
            f[12] = D.x; f[13] = D.y; f[14] = D.z; f[15] = D.w;
        } else {
            const float* bl = &rawL[(r << 6) + 56];
            float4 A = *reinterpret_cast<const float4*>(bl);
            float4 B = *reinterpret_cast<const float4*>(bl + 4);
            const float* br = &rawR[r << 3];
            float4 C = *reinterpret_cast<const float4*>(br);
            float2 D = *reinterpret_cast<const float2*>(br + 4);
            f[0] = A.x; f[1] = A.y; f[2] = A.z; f[3] = A.w;
            f[4] = B.x; f[5] = B.y; f[6] = B.z; f[7] = B.w;
            f[8] = C.x; f[9] = C.y; f[10] = C.z; f[11] = C.w;
            f[12] = D.x; f[13] = D.y; f[14] = 0.f; f[15] = 0.f;
        }
        float lo[4], hi[4];
#pragma unroll
        for (int i = 0; i < 4; ++i) {
            float alo = 0.f, ahi = 0.f;
#pragma unroll
            for (int t = 0; t < 8; ++t) {
                float v = f[2 * i + 7 - t];   // max index 13
                alo = fmaf(DEC_LO[t], v, alo);
                ahi = fmaf(DEC_HI[t], v, ahi);
            }
            lo[i] = alo; hi[i] = ahi;
        }
        int c4 = 4 * q;
        *reinterpret_cast<float4*>(&RB[r][c4]) = make_float4(lo[0], lo[1], lo[2], lo[3]);
        *reinterpret_cast<float4*>(&RB[r][32 + c4]) = make_float4(hi[0], hi[1], hi[2], hi[3]);
    }
    __syncthreads();

    // col dwt: thread owns (jj -> output c=jw, 4 consecutive d=jh)
    int jj = tid & 31, g = tid >> 5;
    int jw = jw0 + jj;
    float mh = 0.f, mv = 0.f, md = 0.f;
#pragma unroll
    for (int pass = 0; pass < 2; ++pass) {
        int rbase = 8 * g + 4 * pass;
        float L[10], H[10];
#pragma unroll
        for (int rr = 0; rr < 10; ++rr) {
            L[rr] = RB[rbase + rr][jj];
            H[rr] = RB[rbase + rr][32 + jj];
        }
        float va[2], vh_[2], vv_[2], vd_[2];
#pragma unroll
        for (int k = 0; k < 2; ++k) {
            float vaa = 0.f, vda = 0.f, vad = 0.f, vdd = 0.f;
#pragma unroll
            for (int t = 0; t < 8; ++t) {
                float l = L[2 * k + 7 - t];
                float h = H[2 * k + 7 - t];
                vaa = fmaf(DEC_LO[t], l, vaa);
                vda = fmaf(DEC_HI[t], l, vda);
                vad = fmaf(DEC_LO[t], h, vad);
                vdd = fmaf(DEC_HI[t], h, vdd);
            }
            va[k] = vaa; vh_[k] = vda; vv_[k] = vad; vd_[k] = vdd;
        }
        int jh = jh0 + 4 * g + 2 * pass;     // first of the pair (even)
        if (jw < Nc && jh < Nc) {
            size_t o = ((size_t)m * Nc + jw) * Nc + jh;   // TRANSPOSED layout
            if (jh + 1 < Nc) {
                *reinterpret_cast<float2*>(aa + o) = make_float2(va[0], va[1]);
                *reinterpret_cast<float2*>(da + o) = make_float2(vh_[0], vh_[1]);
                *reinterpret_cast<float2*>(ad + o) = make_float2(vv_[0], vv_[1]);
                *reinterpret_cast<float2*>(dd + o) = make_float2(vd_[0], vd_[1]);
                mh = fmaxf(mh, fmaxf(fabsf(vh_[0]), fabsf(vh_[1])));
                mv = fmaxf(mv, fmaxf(fabsf(vv_[0]), fabsf(vv_[1])));
                md = fmaxf(md, fmaxf(fabsf(vd_[0]), fabsf(vd_[1])));
            } else {
                aa[o] = va[0]; da[o] = vh_[0]; ad[o] = vv_[0]; dd[o] = vd_[0];
                mh = fmaxf(mh, fabsf(vh_[0]));
                mv = fmaxf(mv, fabsf(vv_[0]));
                md = fmaxf(md, fabsf(vd_[0]));
            }
        }
    }
#pragma unroll
    for (int off = 32; off; off >>= 1) {
        mh = fmaxf(mh, __shfl_down(mh, off));
        mv = fmaxf(mv, __shfl_down(mv, off));
        md = fmaxf(md, __shfl_down(md, off));
    }
    __shared__ float sm[3][4];
    if (ln == 0) { sm[0][wv] = mh; sm[1][wv] = mv; sm[2][wv] = md; }
    __syncthreads();
    if (tid == 0) {
        float A = fmaxf(fmaxf(sm[0][0], sm[0][1]), fmaxf(sm[0][2], sm[0][3]));
        float B = fmaxf(fmaxf(sm[1][0], sm[1][1]), fmaxf(sm[1][2], sm[1][3]));
        float C = fmaxf(fmaxf(sm[2][0], sm[2][1]), fmaxf(sm[2][2], sm[2][3]));
        atomicMax(mx_da + m, __float_as_uint(A));
        atomicMax(mx_ad + m, __float_as_uint(B));
        atomicMax(mx_dd + m, __float_as_uint(C));
    }
}

// ===================== Kernel B: fused 2D IDWT ====================
// Inputs Z[c][d] n x n (d contiguous). Pass 1 synthesizes along d
// (CONTIGUOUS loads: 3 x float2 + 1 scalar per band on interior blocks;
// scalar-clamped path on the one boundary block-row). Pass 2 along c.
// Output R[d2][c2] (c2 contiguous) -> coalesced row stores.
__global__ __launch_bounds__(256, 4) void fused_idwt2_k(
    const float* __restrict__ a, const float* __restrict__ h,
    const float* __restrict__ v, const float* __restrict__ d,
    const unsigned* __restrict__ mxh, const unsigned* __restrict__ mxv,
    const unsigned* __restrict__ mxd,
    int n, int Ho, int tiles, float* __restrict__ out)
{
    int b = blockIdx.x;
    int tx = b % tiles, ty = (b / tiles) % tiles, m = b / (tiles * tiles);
    int i0 = ty * TO, u0 = tx * TO;
    int jr0 = i0 >> 1, jc0 = u0 >> 1;        // jr0: d-freq base, jc0: c-freq base

    __shared__ float LH[TO][71];   // [d2-local][c-local lo | 35+ hi]

    int tid = threadIdx.x;
    float th_h = 0.2f * (1.5f * __uint_as_float(mxh[m]));
    float th_v = 0.2f * (1.5f * __uint_as_float(mxv[m]));
    float th_d = 0.2f * (1.5f * __uint_as_float(mxd[m]));
    const float* am = a + (size_t)m * n * n;
    const float* hm = h + (size_t)m * n * n;
    const float* vm = v + (size_t)m * n * n;
    const float* dm = d + (size_t)m * n * n;

    bool interior = (jr0 + 34 <= n - 1);     // block-uniform

    // pass 1 along d: 8 groups of 8 d2-rows x 35 jc = 280 tasks
    auto coltask = [&](int task) {
        int g = task / 35, jc = task % 35;
        int jcg = jc0 + jc; if (jcg > n - 1) jcg = n - 1;
        int base = jr0 + 4 * g;
        float Ar[7], Hr[7], Vr[7], Dr[7];
        if (interior) {
            size_t ob = (size_t)jcg * n + base;   // even -> 8B-aligned
            const float* ap = am + ob;
            const float* hp = hm + ob;
            const float* vp = vm + ob;
            const float* dp = dm + ob;
            float2 t0, t1, t2;
            t0 = *reinterpret_cast<const float2*>(ap);
            t1 = *reinterpret_cast<const float2*>(ap + 2);
            t2 = *reinterpret_cast<const float2*>(ap + 4);
            Ar[0]=t0.x; Ar[1]=t0.y; Ar[2]=t1.x; Ar[3]=t1.y; Ar[4]=t2.x; Ar[5]=t2.y;
            Ar[6] = ap[6];
            t0 = *reinterpret_cast<const float2*>(hp);
            t1 = *reinterpret_cast<const float2*>(hp + 2);
            t2 = *reinterpret_cast<const float2*>(hp + 4);
            Hr[0]=t0.x; Hr[1]=t0.y; Hr[2]=t1.x; Hr[3]=t1.y; Hr[4]=t2.x; Hr[5]=t2.y;
            Hr[6] = hp[6];
            t0 = *reinterpret_cast<const float2*>(vp);
            t1 = *reinterpret_cast<const float2*>(vp + 2);
            t2 = *reinterpret_cast<const float2*>(vp + 4);
            Vr[0]=t0.x; Vr[1]=t0.y; Vr[2]=t1.x; Vr[3]=t1.y; Vr[4]=t2.x; Vr[5]=t2.y;
            Vr[6] = vp[6];
            t0 = *reinterpret_cast<const float2*>(dp);
            t1 = *reinterpret_cast<const float2*>(dp + 2);
            t2 = *reinterpret_cast<const float2*>(dp + 4);
            Dr[0]=t0.x; Dr[1]=t0.y; Dr[2]=t1.x; Dr[3]=t1.y; Dr[4]=t2.x; Dr[5]=t2.y;
            Dr[6] = dp[6];
        } else {
#pragma unroll
            for (int rr = 0; rr < 7; ++rr) {
                int jr = base + rr; if (jr > n - 1) jr = n - 1;
                size_t o = (size_t)jcg * n + jr;
                Ar[rr] = am[o]; Hr[rr] = hm[o]; Vr[rr] = vm[o]; Dr[rr] = dm[o];
            }
        }
#pragma unroll
        for (int rr = 0; rr < 7; ++rr) {
            Hr[rr] = soft_enh(Hr[rr], th_h);
            Vr[rr] = soft_enh(Vr[rr], th_v);
            Dr[rr] = soft_enh(Dr[rr], th_d);
        }
#pragma unroll
        for (int pass = 0; pass < 2; ++pass) {
            int P = 2 * g + pass;                // 4-output group index
            float acc_lo[4], acc_hi[4];
#pragma unroll
            for (int k = 0; k < 4; ++k) { acc_lo[k] = 0.f; acc_hi[k] = 0.f; }
#pragma unroll
            for (int rl = 0; rl < 5; ++rl) {
                int rr = 2 * pass + rl;          // row index into preload
                float av = Ar[rr], hv = Hr[rr], vv = Vr[rr], dv = Dr[rr];
#pragma unroll
                for (int t = 0; t < 8; ++t) {
                    int k = 2 * rl + t - 6;      // compile-time per iteration
                    if (k >= 0 && k < 4) {
                        acc_lo[k] = fmaf(REC_LO[t], av, fmaf(REC_HI[t], hv, acc_lo[k]));
                        acc_hi[k] = fmaf(REC_LO[t], vv, fmaf(REC_HI[t], dv, acc_hi[k]));
                    }
                }
            }
#pragma unroll
            for (int k = 0; k < 4; ++k) {
                LH[4 * P + k][jc] = acc_lo[k];
                LH[4 * P + k][35 + jc] = acc_hi[k];
            }
        }
    };
    coltask(tid);                  // tid < 280 always (256 threads)
    if (tid + 256 < 8 * 35) coltask(tid + 256);
    __syncthreads();

    // pass 2 along c -> out tile (coalesced along c2)
    for (int e = tid; e < TO * TO; e += 256) {
        int il = e >> 6, ul = e & 63;
        int t0 = ul & 1;
        float acc = 0.f;
#pragma unroll
        for (int s = 0; s < 4; ++s) {
            int t = t0 + 2 * s;
            int c = (ul + 6 - t) >> 1;
            acc = fmaf(REC_LO[t], LH[il][c], acc);
            acc = fmaf(REC_HI[t], LH[il][35 + c], acc);
        }
        int gi = i0 + il, gu = u0 + ul;
        if (gi < Ho && gu < Ho)
            out[((size_t)m * Ho + gi) * Ho + gu] = acc;
    }
}

extern "C" void kernel_launch(void* const* d_in, const int* in_sizes, int n_in,
                              void* d_out, int out_size, void* d_ws, size_t ws_size,
                              hipStream_t stream) {
    const float* x = (const float*)d_in[0];
    float* out = (float*)d_out;
    float* ws = (float*)d_ws;

    const int M = 96, S1 = 510, N1 = 258, N2 = 132;
    const long S_l1 = (long)M * N1 * N1;
    const long S_l2 = (long)M * N2 * N2;

    float* aa1 = ws;
    float* h1  = aa1 + S_l1;
    float* v1  = h1 + S_l1;
    float* d1  = v1 + S_l1;
    float* a1r = d1 + S_l1;
    float* a2  = a1r + S_l1;
    float* h2  = a2 + S_l2;
    float* v2  = h2 + S_l2;
    float* d2  = v2 + S_l2;
    unsigned* th = (unsigned*)(d2 + S_l2);   // 6*96 uints

    long need = 5 * S_l1 + 4 * S_l2 + 576;
    if (ws_size < (size_t)need * sizeof(float)) return;

    unsigned *th_h1 = th, *th_v1 = th + 96, *th_d1 = th + 192;
    unsigned *th_h2 = th + 288, *th_v2 = th + 384, *th_d2 = th + 480;

    hipMemsetAsync(th, 0, 576 * sizeof(unsigned), stream);

    // All band arrays live in transposed [c][d] layout (see kernel docs).
    // Separability keeps the same two kernels correct at both levels with
    // unchanged argument order; final output lands in normal layout.
    fused_dwt2_k<<<9 * 9 * M, 256, 0, stream>>>(x, S1, N1, 9, aa1, h1, v1, d1,
                                                th_h1, th_v1, th_d1);
    fused_dwt2_k<<<5 * 5 * M, 256, 0, stream>>>(aa1, N1, N2, 5, a2, h2, v2, d2,
                                                th_h2, th_v2, th_d2);
    fused_idwt2_k<<<5 * 5 * M, 256, 0, stream>>>(a2, h2, v2, d2, th_h2, th_v2, th_d2,
                                                 N2, N1, 5, a1r);
    fused_idwt2_k<<<8 * 8 * M, 256, 0, stream>>>(a1r, h1, v1, d1, th_h1, th_v1, th_d1,
                                                 N1, S1, 8, out);
}

// Round 6
// 326.187 us; speedup vs baseline: 1.1950x; 1.1950x over previous
//
#include <hip/hip_runtime.h>

// db4 filters as compile-time constants
__device__ constexpr float DEC_LO[8] = {
    -0.010597401784997278f, 0.032883011666982945f, 0.030841381835986965f,
    -0.18703481171888114f, -0.02798376941698385f, 0.6308807679295904f,
    0.7148465705525415f, 0.23037781330885523f};
__device__ constexpr float DEC_HI[8] = {
    -0.23037781330885523f, 0.7148465705525415f, -0.6308807679295904f,
    -0.02798376941698385f, 0.18703481171888114f, 0.030841381835986965f,
    -0.032883011666982945f, -0.010597401784997278f};
__device__ constexpr float REC_LO[8] = {
    0.23037781330885523f, 0.7148465705525415f, 0.6308807679295904f,
    -0.02798376941698385f, -0.18703481171888114f, 0.030841381835986965f,
    0.032883011666982945f, -0.010597401784997278f};
__device__ constexpr float REC_HI[8] = {
    -0.010597401784997278f, -0.032883011666982945f, 0.030841381835986965f,
    0.18703481171888114f, -0.02798376941698385f, -0.6308807679295904f,
    0.7148465705525415f, -0.23037781330885523f};

__device__ __forceinline__ float soft_enh(float v, float th) {
    float e = 1.5f * v;
    float a = fabsf(e) - th;
    return a > 0.0f ? copysignf(a, e) : 0.0f;
}

#define TB 32
#define TO 64

// ===================== Kernel A: fused 2D DWT (R2 version, best measured)
// Row-DWT: 560 row-tasks per block, 2-3 per thread, all global loads for a
// thread's tasks batched before compute. Normal [row][col] band layout;
// stores coalesced across lanes (jj consecutive -> consecutive addresses).
__global__ __launch_bounds__(256, 4) void fused_dwt2_k(
    const float* __restrict__ x, int S, int Nc, int tiles,
    float* __restrict__ aa, float* __restrict__ da,
    float* __restrict__ ad, float* __restrict__ dd,
    unsigned* __restrict__ mx_da, unsigned* __restrict__ mx_ad,
    unsigned* __restrict__ mx_dd)
{
    int b = blockIdx.x;
    int tx = b % tiles, ty = (b / tiles) % tiles, m = b / (tiles * tiles);
    int jh0 = ty * TB, jw0 = tx * TB;
    int r0 = 2 * jh0 - 6, c0 = 2 * jw0 - 6;
    const float* xm = x + (size_t)m * S * S;

    __shared__ float RB[70][68];   // 19,040 B

    int tid = threadIdx.x;
    bool colv = (c0 >= 0) && (c0 + 71 < S);   // vector path: cols in-bounds

    int e0 = tid, e1 = tid + 256, e2 = tid + 512;
    bool has2 = (e2 < 560);

    auto prow = [&](int e) -> const float* {
        int pr = r0 + (e >> 3);
        pr = pr < 0 ? -1 - pr : pr;
        pr = pr >= S ? 2 * S - 1 - pr : pr;
        return xm + (size_t)pr * S;
    };

    float f0[16], f1[16], f2[16];
    if (colv) {
        const float* s0 = prow(e0) + (c0 + 8 * (e0 & 7));
        const float* s1 = prow(e1) + (c0 + 8 * (e1 & 7));
#pragma unroll
        for (int i = 0; i < 8; ++i) {
            float2 v = *reinterpret_cast<const float2*>(s0 + 2 * i);
            f0[2 * i] = v.x; f0[2 * i + 1] = v.y;
        }
#pragma unroll
        for (int i = 0; i < 8; ++i) {
            float2 v = *reinterpret_cast<const float2*>(s1 + 2 * i);
            f1[2 * i] = v.x; f1[2 * i + 1] = v.y;
        }
        if (has2) {
            const float* s2 = prow(e2) + (c0 + 8 * (e2 & 7));
#pragma unroll
            for (int i = 0; i < 8; ++i) {
                float2 v = *reinterpret_cast<const float2*>(s2 + 2 * i);
                f2[2 * i] = v.x; f2[2 * i + 1] = v.y;
            }
        }
    } else {
        auto gath = [&](int e, float* f) {
            const float* row = prow(e);
            int base = c0 + 8 * (e & 7);
#pragma unroll
            for (int i = 0; i < 16; ++i) {
                int p = base + i;
                p = p < 0 ? -1 - p : p;
                p = p >= S ? 2 * S - 1 - p : p;
                f[i] = row[p];
            }
        };
        gath(e0, f0);
        gath(e1, f1);
        if (has2) gath(e2, f2);
    }

    auto rdwt = [&](int e, const float* f) {
        float lo[4], hi[4];
#pragma unroll
        for (int i = 0; i < 4; ++i) {
            float alo = 0.f, ahi = 0.f;
#pragma unroll
            for (int t = 0; t < 8; ++t) {
                float v = f[2 * i + 7 - t];
                alo = fmaf(DEC_LO[t], v, alo);
                ahi = fmaf(DEC_HI[t], v, ahi);
            }
            lo[i] = alo; hi[i] = ahi;
        }
        int r = e >> 3, c4 = 4 * (e & 7);
        *reinterpret_cast<float4*>(&RB[r][c4]) = make_float4(lo[0], lo[1], lo[2], lo[3]);
        *reinterpret_cast<float4*>(&RB[r][32 + c4]) = make_float4(hi[0], hi[1], hi[2], hi[3]);
    };
    rdwt(e0, f0);
    rdwt(e1, f1);
    if (has2) rdwt(e2, f2);
    __syncthreads();

    // col dwt: thread owns (jj, 4 consecutive ii), two register-light passes
    int jj = tid & 31, g = tid >> 5;
    int jw = jw0 + jj;
    float mh = 0.f, mv = 0.f, md = 0.f;
#pragma unroll
    for (int pass = 0; pass < 2; ++pass) {
        int rbase = 8 * g + 4 * pass;
        float L[10], H[10];
#pragma unroll
        for (int rr = 0; rr < 10; ++rr) {
            L[rr] = RB[rbase + rr][jj];
            H[rr] = RB[rbase + rr][32 + jj];
        }
#pragma unroll
        for (int k = 0; k < 2; ++k) {
            float vaa = 0.f, vda = 0.f, vad = 0.f, vdd = 0.f;
#pragma unroll
            for (int t = 0; t < 8; ++t) {
                float l = L[2 * k + 7 - t];
                float h = H[2 * k + 7 - t];
                vaa = fmaf(DEC_LO[t], l, vaa);
                vda = fmaf(DEC_HI[t], l, vda);
                vad = fmaf(DEC_LO[t], h, vad);
                vdd = fmaf(DEC_HI[t], h, vdd);
            }
            int jh = jh0 + 4 * g + 2 * pass + k;
            if (jh < Nc && jw < Nc) {
                size_t o = ((size_t)m * Nc + jh) * Nc + jw;
                aa[o] = vaa; da[o] = vda; ad[o] = vad; dd[o] = vdd;
                mh = fmaxf(mh, fabsf(vda));
                mv = fmaxf(mv, fabsf(vad));
                md = fmaxf(md, fabsf(vdd));
            }
        }
    }
#pragma unroll
    for (int off = 32; off; off >>= 1) {
        mh = fmaxf(mh, __shfl_down(mh, off));
        mv = fmaxf(mv, __shfl_down(mv, off));
        md = fmaxf(md, __shfl_down(md, off));
    }
    __shared__ float sm[3][4];
    int wv = tid >> 6, ln = tid & 63;
    if (ln == 0) { sm[0][wv] = mh; sm[1][wv] = mv; sm[2][wv] = md; }
    __syncthreads();
    if (tid == 0) {
        float A = fmaxf(fmaxf(sm[0][0], sm[0][1]), fmaxf(sm[0][2], sm[0][3]));
        float B = fmaxf(fmaxf(sm[1][0], sm[1][1]), fmaxf(sm[1][2], sm[1][3]));
        float C = fmaxf(fmaxf(sm[2][0], sm[2][1]), fmaxf(sm[2][2], sm[2][3]));
        atomicMax(mx_da + m, __float_as_uint(A));
        atomicMax(mx_ad + m, __float_as_uint(B));
        atomicMax(mx_dd + m, __float_as_uint(C));
    }
}

// ============ Kernel B: fused IDWT2+IDWT1 (full reconstruction) ============
// Each block builds a 64x64 output tile. It synthesizes its own 35x35 a1r
// patch in LDS from a 21x21 level-2 band patch (phases 1a/1b = idwt2, ~20%
// redundant vs exclusive tiling but level-2 bands are L2/L3-resident), then
// runs idwt1 (phases 2a/2b) with the a1r read from LDS. Eliminates the a1r
// HBM round-trip and one dispatch. h1/v1/d1 loads (the real HBM traffic)
// are issued up front so their latency hides under the level-2 compute.
// Tap accumulation order matches the old two-kernel pair exactly.
__global__ __launch_bounds__(256, 4) void fused_irec_k(
    const float* __restrict__ a2, const float* __restrict__ h2,
    const float* __restrict__ v2, const float* __restrict__ d2,
    const float* __restrict__ h1, const float* __restrict__ v1,
    const float* __restrict__ d1,
    const unsigned* __restrict__ mx2h, const unsigned* __restrict__ mx2v,
    const unsigned* __restrict__ mx2d,
    const unsigned* __restrict__ mx1h, const unsigned* __restrict__ mx1v,
    const unsigned* __restrict__ mx1d,
    int n2, int n1, int Ho, int tiles, float* __restrict__ out)
{
    int b = blockIdx.x;
    int tx = b % tiles, ty = (b / tiles) % tiles, m = b / (tiles * tiles);
    int i0 = ty * TO, u0 = tx * TO;
    int jr0 = i0 >> 1, jc0 = u0 >> 1;        // level-1 half coords (even)
    int q0r = jr0 >> 1, q0c = jc0 >> 1;      // level-2 quarter coords (even)

    __shared__ float AH[35][44];   // lvl2 row-synth: [p][cc]=lo, [p][22+cc]=hi
    __shared__ float AR[35][36];   // a1r patch rows jr0..jr0+34, cols jc0..jc0+34
    __shared__ float LH[64][71];   // idwt1 row-synth (as before)

    int tid = threadIdx.x;
    float th2_h = 0.2f * (1.5f * __uint_as_float(mx2h[m]));
    float th2_v = 0.2f * (1.5f * __uint_as_float(mx2v[m]));
    float th2_d = 0.2f * (1.5f * __uint_as_float(mx2d[m]));
    float th1_h = 0.2f * (1.5f * __uint_as_float(mx1h[m]));
    float th1_v = 0.2f * (1.5f * __uint_as_float(mx1v[m]));
    float th1_d = 0.2f * (1.5f * __uint_as_float(mx1d[m]));
    const float* a2m = a2 + (size_t)m * n2 * n2;
    const float* h2m = h2 + (size_t)m * n2 * n2;
    const float* v2m = v2 + (size_t)m * n2 * n2;
    const float* d2m = d2 + (size_t)m * n2 * n2;
    const float* h1m = h1 + (size_t)m * n1 * n1;
    const float* v1m = v1 + (size_t)m * n1 * n1;
    const float* d1m = d1 + (size_t)m * n1 * n1;

    // ---- phase 1a loads (issued FIRST so 1a's wait leaves hvd in flight)
    int g2 = tid / 21, cc = tid % 21;        // 189 tasks: g2 0..8
    bool act1a = (tid < 189);
    float A2r[5], H2r[5], V2r[5], D2r[5];
    if (act1a) {
        int c2 = q0c + cc; if (c2 > n2 - 1) c2 = n2 - 1;
#pragma unroll
        for (int rl = 0; rl < 5; ++rl) {
            int j2 = q0r + 2 * g2 + rl; if (j2 > n2 - 1) j2 = n2 - 1;
            size_t o = (size_t)j2 * n2 + c2;
            A2r[rl] = a2m[o]; H2r[rl] = h2m[o];
            V2r[rl] = v2m[o]; D2r[rl] = d2m[o];
        }
    }

    // ---- phase 0: hoist this thread's h1/v1/d1 rows (used in phase 2a).
    // Lanes have consecutive jcA -> coalesced; latency hides under 1a/1b.
    int gA = tid / 35, jcA = tid % 35;       // tid<256 -> gA<=7
    int jcg = jc0 + jcA; if (jcg > n1 - 1) jcg = n1 - 1;
    int baseA = jr0 + 4 * gA;
    float Hg[7], Vg[7], Dg[7];
#pragma unroll
    for (int rr = 0; rr < 7; ++rr) {
        int jr = baseA + rr; if (jr > n1 - 1) jr = n1 - 1;
        size_t o = (size_t)jr * n1 + jcg;
        Hg[rr] = h1m[o]; Vg[rr] = v1m[o]; Dg[rr] = d1m[o];
    }

    // ---- phase 1a compute: lvl2 synth along rows -> AH
    if (act1a) {
#pragma unroll
        for (int rl = 0; rl < 5; ++rl) {
            H2r[rl] = soft_enh(H2r[rl], th2_h);
            V2r[rl] = soft_enh(V2r[rl], th2_v);
            D2r[rl] = soft_enh(D2r[rl], th2_d);
        }
        float alo[4], ahi[4];
#pragma unroll
        for (int k = 0; k < 4; ++k) { alo[k] = 0.f; ahi[k] = 0.f; }
#pragma unroll
        for (int rl = 0; rl < 5; ++rl) {
#pragma unroll
            for (int t = 0; t < 8; ++t) {
                int k = 2 * rl + t - 6;
                if (k >= 0 && k < 4) {
                    alo[k] = fmaf(REC_LO[t], A2r[rl], fmaf(REC_HI[t], H2r[rl], alo[k]));
                    ahi[k] = fmaf(REC_LO[t], V2r[rl], fmaf(REC_HI[t], D2r[rl], ahi[k]));
                }
            }
        }
#pragma unroll
        for (int k = 0; k < 4; ++k) {
            int p = 4 * g2 + k;
            if (p < 35) { AH[p][cc] = alo[k]; AH[p][22 + cc] = ahi[k]; }
        }
    }
    __syncthreads();

    // ---- phase 1b: lvl2 synth along cols -> AR (1225 outputs)
    for (int e = tid; e < 1225; e += 256) {
        int p = e / 35, cl = e % 35;
        int t0 = cl & 1;
        float acc = 0.f;
#pragma unroll
        for (int s = 0; s < 4; ++s) {
            int t = t0 + 2 * s;
            int c = (cl + 6 - t) >> 1;
            acc = fmaf(REC_LO[t], AH[p][c], acc);
            acc = fmaf(REC_HI[t], AH[p][22 + c], acc);
        }
        AR[p][cl] = acc;
    }
    __syncthreads();

    // ---- phase 2a: idwt1 synth along rows -> LH (280 tasks)
    {   // round 1: task tid (hoisted hvd regs, a1r from LDS)
        float Ar[7], Hs[7], Vs[7], Ds[7];
#pragma unroll
        for (int rr = 0; rr < 7; ++rr) {
            Ar[rr] = AR[4 * gA + rr][jcA];
            Hs[rr] = soft_enh(Hg[rr], th1_h);
            Vs[rr] = soft_enh(Vg[rr], th1_v);
            Ds[rr] = soft_enh(Dg[rr], th1_d);
        }
#pragma unroll
        for (int pass = 0; pass < 2; ++pass) {
            int P = 2 * gA + pass;
            float acc_lo[4], acc_hi[4];
#pragma unroll
            for (int k = 0; k < 4; ++k) { acc_lo[k] = 0.f; acc_hi[k] = 0.f; }
#pragma unroll
            for (int rl = 0; rl < 5; ++rl) {
                int rr = 2 * pass + rl;
                float av = Ar[rr], hv = Hs[rr], vv = Vs[rr], dv = Ds[rr];
#pragma unroll
                for (int t = 0; t < 8; ++t) {
                    int k = 2 * rl + t - 6;
                    if (k >= 0 && k < 4) {
                        acc_lo[k] = fmaf(REC_LO[t], av, fmaf(REC_HI[t], hv, acc_lo[k]));
                        acc_hi[k] = fmaf(REC_LO[t], vv, fmaf(REC_HI[t], dv, acc_hi[k]));
                    }
                }
            }
#pragma unroll
            for (int k = 0; k < 4; ++k) {
                LH[4 * P + k][jcA] = acc_lo[k];
                LH[4 * P + k][35 + jcA] = acc_hi[k];
            }
        }
    }
    if (tid < 24) {  // round 2: tasks 256..279 (gB==7), loads issued here
        int tk = tid + 256;
        int gB = tk / 35, jcB = tk % 35;
        int jcgB = jc0 + jcB; if (jcgB > n1 - 1) jcgB = n1 - 1;
        int baseB = jr0 + 4 * gB;
        float Ar[7], Hs[7], Vs[7], Ds[7];
#pragma unroll
        for (int rr = 0; rr < 7; ++rr) {
            int jr = baseB + rr; if (jr > n1 - 1) jr = n1 - 1;
            size_t o = (size_t)jr * n1 + jcgB;
            Ar[rr] = AR[4 * gB + rr][jcB];
            Hs[rr] = soft_enh(h1m[o], th1_h);
            Vs[rr] = soft_enh(v1m[o], th1_v);
            Ds[rr] = soft_enh(d1m[o], th1_d);
        }
#pragma unroll
        for (int pass = 0; pass < 2; ++pass) {
            int P = 2 * gB + pass;
            float acc_lo[4], acc_hi[4];
#pragma unroll
            for (int k = 0; k < 4; ++k) { acc_lo[k] = 0.f; acc_hi[k] = 0.f; }
#pragma unroll
            for (int rl = 0; rl < 5; ++rl) {
                int rr = 2 * pass + rl;
                float av = Ar[rr], hv = Hs[rr], vv = Vs[rr], dv = Ds[rr];
#pragma unroll
                for (int t = 0; t < 8; ++t) {
                    int k = 2 * rl + t - 6;
                    if (k >= 0 && k < 4) {
                        acc_lo[k] = fmaf(REC_LO[t], av, fmaf(REC_HI[t], hv, acc_lo[k]));
                        acc_hi[k] = fmaf(REC_LO[t], vv, fmaf(REC_HI[t], dv, acc_hi[k]));
                    }
                }
            }
#pragma unroll
            for (int k = 0; k < 4; ++k) {
                LH[4 * P + k][jcB] = acc_lo[k];
                LH[4 * P + k][35 + jcB] = acc_hi[k];
            }
        }
    }
    __syncthreads();

    // ---- phase 2b: idwt1 synth along cols -> out tile (coalesced stores)
    for (int e = tid; e < TO * TO; e += 256) {
        int il = e >> 6, ul = e & 63;
        int t0 = ul & 1;
        float acc = 0.f;
#pragma unroll
        for (int s = 0; s < 4; ++s) {
            int t = t0 + 2 * s;
            int c = (ul + 6 - t) >> 1;
            acc = fmaf(REC_LO[t], LH[il][c], acc);
            acc = fmaf(REC_HI[t], LH[il][35 + c], acc);
        }
        int gi = i0 + il, gu = u0 + ul;
        if (gi < Ho && gu < Ho)
            out[((size_t)m * Ho + gi) * Ho + gu] = acc;
    }
}

extern "C" void kernel_launch(void* const* d_in, const int* in_sizes, int n_in,
                              void* d_out, int out_size, void* d_ws, size_t ws_size,
                              hipStream_t stream) {
    const float* x = (const float*)d_in[0];
    float* out = (float*)d_out;
    float* ws = (float*)d_ws;

    const int M = 96, S1 = 510, N1 = 258, N2 = 132;
    const long S_l1 = (long)M * N1 * N1;
    const long S_l2 = (long)M * N2 * N2;

    float* aa1 = ws;
    float* h1  = aa1 + S_l1;
    float* v1  = h1 + S_l1;
    float* d1  = v1 + S_l1;
    float* a2  = d1 + S_l1;
    float* h2  = a2 + S_l2;
    float* v2  = h2 + S_l2;
    float* d2  = v2 + S_l2;
    unsigned* th = (unsigned*)(d2 + S_l2);   // 6*96 uints

    long need = 4 * S_l1 + 4 * S_l2 + 576;
    if (ws_size < (size_t)need * sizeof(float)) return;

    unsigned *th_h1 = th, *th_v1 = th + 96, *th_d1 = th + 192;
    unsigned *th_h2 = th + 288, *th_v2 = th + 384, *th_d2 = th + 480;

    hipMemsetAsync(th, 0, 576 * sizeof(unsigned), stream);

    // Level 1 decomposition: x(510) -> bands(258). 9x9 tiles per image.
    fused_dwt2_k<<<9 * 9 * M, 256, 0, stream>>>(x, S1, N1, 9, aa1, h1, v1, d1,
                                                th_h1, th_v1, th_d1);
    // Level 2 decomposition: aa1(258) -> bands(132). 5x5 tiles.
    fused_dwt2_k<<<5 * 5 * M, 256, 0, stream>>>(aa1, N1, N2, 5, a2, h2, v2, d2,
                                                th_h2, th_v2, th_d2);
    // Fused reconstruction: lvl2 bands + lvl1 details -> out(510). 8x8 tiles.
    fused_irec_k<<<8 * 8 * M, 256, 0, stream>>>(a2, h2, v2, d2, h1, v1, d1,
                                                th_h2, th_v2, th_d2,
                                                th_h1, th_v1, th_d1,
                                                N2, N1, S1, 8, out);
}

// Round 7
// 314.198 us; speedup vs baseline: 1.2406x; 1.0382x over previous
//
#include <hip/hip_runtime.h>

// db4 filters as compile-time constants
__device__ constexpr float DEC_LO[8] = {
    -0.010597401784997278f, 0.032883011666982945f, 0.030841381835986965f,
    -0.18703481171888114f, -0.02798376941698385f, 0.6308807679295904f,
    0.7148465705525415f, 0.23037781330885523f};
__device__ constexpr float DEC_HI[8] = {
    -0.23037781330885523f, 0.7148465705525415f, -0.6308807679295904f,
    -0.02798376941698385f, 0.18703481171888114f, 0.030841381835986965f,
    -0.032883011666982945f, -0.010597401784997278f};
__device__ constexpr float REC_LO[8] = {
    0.23037781330885523f, 0.7148465705525415f, 0.6308807679295904f,
    -0.02798376941698385f, -0.18703481171888114f, 0.030841381835986965f,
    0.032883011666982945f, -0.010597401784997278f};
__device__ constexpr float REC_HI[8] = {
    -0.010597401784997278f, -0.032883011666982945f, 0.030841381835986965f,
    0.18703481171888114f, -0.02798376941698385f, -0.6308807679295904f,
    0.7148465705525415f, -0.23037781330885523f};

__device__ __forceinline__ float soft_enh(float v, float th) {
    float e = 1.5f * v;
    float a = fabsf(e) - th;
    return a > 0.0f ? copysignf(a, e) : 0.0f;
}

// XCD-chunked bijective swizzle. All grids here are divisible by 8, so
// nb=(b%8)*(nwg/8)+b/8 is bijective; consecutive original block indices
// (adjacent tiles sharing input rows / band lines) land on ONE XCD's L2
// instead of being round-robined across all 8.
__device__ __forceinline__ int xcd_swz(int b, int nwg) {
    int cpx = nwg >> 3;
    return (b & 7) * cpx + (b >> 3);
}

#define TB 32
#define TO 64

// ===================== Kernel A: fused 2D DWT =====================
// R2/R6 structure (best measured). New: ldX/ldB row strides. Bands are
// written with ldB a multiple of 32 floats so every 32-float tile-row
// store is exactly one aligned 128B line (kills partial-line write
// amplification: WRITE_SIZE 120.5 -> ~103 MB predicted).
__global__ __launch_bounds__(256, 4) void fused_dwt2_k(
    const float* __restrict__ x, int S, int ldX, int Nc, int ldB, int tiles,
    float* __restrict__ aa, float* __restrict__ da,
    float* __restrict__ ad, float* __restrict__ dd,
    unsigned* __restrict__ mx_da, unsigned* __restrict__ mx_ad,
    unsigned* __restrict__ mx_dd)
{
    int b = xcd_swz(blockIdx.x, gridDim.x);
    int tx = b % tiles, ty = (b / tiles) % tiles, m = b / (tiles * tiles);
    int jh0 = ty * TB, jw0 = tx * TB;
    int r0 = 2 * jh0 - 6, c0 = 2 * jw0 - 6;
    const float* xm = x + (size_t)m * S * ldX;

    __shared__ float RB[70][68];   // 19,040 B

    int tid = threadIdx.x;
    bool colv = (c0 >= 0) && (c0 + 71 < S);   // vector path: cols in-bounds

    int e0 = tid, e1 = tid + 256, e2 = tid + 512;
    bool has2 = (e2 < 560);

    auto prow = [&](int e) -> const float* {
        int pr = r0 + (e >> 3);
        pr = pr < 0 ? -1 - pr : pr;
        pr = pr >= S ? 2 * S - 1 - pr : pr;
        return xm + (size_t)pr * ldX;
    };

    float f0[16], f1[16], f2[16];
    if (colv) {
        const float* s0 = prow(e0) + (c0 + 8 * (e0 & 7));
        const float* s1 = prow(e1) + (c0 + 8 * (e1 & 7));
#pragma unroll
        for (int i = 0; i < 8; ++i) {
            float2 v = *reinterpret_cast<const float2*>(s0 + 2 * i);
            f0[2 * i] = v.x; f0[2 * i + 1] = v.y;
        }
#pragma unroll
        for (int i = 0; i < 8; ++i) {
            float2 v = *reinterpret_cast<const float2*>(s1 + 2 * i);
            f1[2 * i] = v.x; f1[2 * i + 1] = v.y;
        }
        if (has2) {
            const float* s2 = prow(e2) + (c0 + 8 * (e2 & 7));
#pragma unroll
            for (int i = 0; i < 8; ++i) {
                float2 v = *reinterpret_cast<const float2*>(s2 + 2 * i);
                f2[2 * i] = v.x; f2[2 * i + 1] = v.y;
            }
        }
    } else {
        auto gath = [&](int e, float* f) {
            const float* row = prow(e);
            int base = c0 + 8 * (e & 7);
#pragma unroll
            for (int i = 0; i < 16; ++i) {
                int p = base + i;
                p = p < 0 ? -1 - p : p;
                p = p >= S ? 2 * S - 1 - p : p;
                f[i] = row[p];
            }
        };
        gath(e0, f0);
        gath(e1, f1);
        if (has2) gath(e2, f2);
    }

    auto rdwt = [&](int e, const float* f) {
        float lo[4], hi[4];
#pragma unroll
        for (int i = 0; i < 4; ++i) {
            float alo = 0.f, ahi = 0.f;
#pragma unroll
            for (int t = 0; t < 8; ++t) {
                float v = f[2 * i + 7 - t];
                alo = fmaf(DEC_LO[t], v, alo);
                ahi = fmaf(DEC_HI[t], v, ahi);
            }
            lo[i] = alo; hi[i] = ahi;
        }
        int r = e >> 3, c4 = 4 * (e & 7);
        *reinterpret_cast<float4*>(&RB[r][c4]) = make_float4(lo[0], lo[1], lo[2], lo[3]);
        *reinterpret_cast<float4*>(&RB[r][32 + c4]) = make_float4(hi[0], hi[1], hi[2], hi[3]);
    };
    rdwt(e0, f0);
    rdwt(e1, f1);
    if (has2) rdwt(e2, f2);
    __syncthreads();

    // col dwt: thread owns (jj, 4 consecutive ii), two register-light passes
    int jj = tid & 31, g = tid >> 5;
    int jw = jw0 + jj;
    float mh = 0.f, mv = 0.f, md = 0.f;
#pragma unroll
    for (int pass = 0; pass < 2; ++pass) {
        int rbase = 8 * g + 4 * pass;
        float L[10], H[10];
#pragma unroll
        for (int rr = 0; rr < 10; ++rr) {
            L[rr] = RB[rbase + rr][jj];
            H[rr] = RB[rbase + rr][32 + jj];
        }
#pragma unroll
        for (int k = 0; k < 2; ++k) {
            float vaa = 0.f, vda = 0.f, vad = 0.f, vdd = 0.f;
#pragma unroll
            for (int t = 0; t < 8; ++t) {
                float l = L[2 * k + 7 - t];
                float h = H[2 * k + 7 - t];
                vaa = fmaf(DEC_LO[t], l, vaa);
                vda = fmaf(DEC_HI[t], l, vda);
                vad = fmaf(DEC_LO[t], h, vad);
                vdd = fmaf(DEC_HI[t], h, vdd);
            }
            int jh = jh0 + 4 * g + 2 * pass + k;
            if (jh < Nc && jw < Nc) {
                size_t o = ((size_t)m * Nc + jh) * ldB + jw;
                aa[o] = vaa; da[o] = vda; ad[o] = vad; dd[o] = vdd;
                mh = fmaxf(mh, fabsf(vda));
                mv = fmaxf(mv, fabsf(vad));
                md = fmaxf(md, fabsf(vdd));
            }
        }
    }
#pragma unroll
    for (int off = 32; off; off >>= 1) {
        mh = fmaxf(mh, __shfl_down(mh, off));
        mv = fmaxf(mv, __shfl_down(mv, off));
        md = fmaxf(md, __shfl_down(md, off));
    }
    __shared__ float sm[3][4];
    int wv = tid >> 6, ln = tid & 63;
    if (ln == 0) { sm[0][wv] = mh; sm[1][wv] = mv; sm[2][wv] = md; }
    __syncthreads();
    if (tid == 0) {
        float A = fmaxf(fmaxf(sm[0][0], sm[0][1]), fmaxf(sm[0][2], sm[0][3]));
        float B = fmaxf(fmaxf(sm[1][0], sm[1][1]), fmaxf(sm[1][2], sm[1][3]));
        float C = fmaxf(fmaxf(sm[2][0], sm[2][1]), fmaxf(sm[2][2], sm[2][3]));
        atomicMax(mx_da + m, __float_as_uint(A));
        atomicMax(mx_ad + m, __float_as_uint(B));
        atomicMax(mx_dd + m, __float_as_uint(C));
    }
}

// ============ Kernel B: fused IDWT2+IDWT1 (R6 structure + strides) ========
__global__ __launch_bounds__(256, 4) void fused_irec_k(
    const float* __restrict__ a2, const float* __restrict__ h2,
    const float* __restrict__ v2, const float* __restrict__ d2,
    const float* __restrict__ h1, const float* __restrict__ v1,
    const float* __restrict__ d1,
    const unsigned* __restrict__ mx2h, const unsigned* __restrict__ mx2v,
    const unsigned* __restrict__ mx2d,
    const unsigned* __restrict__ mx1h, const unsigned* __restrict__ mx1v,
    const unsigned* __restrict__ mx1d,
    int n2, int ld2, int n1, int ld1, int Ho, int tiles,
    float* __restrict__ out)
{
    int b = xcd_swz(blockIdx.x, gridDim.x);
    int tx = b % tiles, ty = (b / tiles) % tiles, m = b / (tiles * tiles);
    int i0 = ty * TO, u0 = tx * TO;
    int jr0 = i0 >> 1, jc0 = u0 >> 1;        // level-1 half coords (even)
    int q0r = jr0 >> 1, q0c = jc0 >> 1;      // level-2 quarter coords (even)

    __shared__ float AH[35][44];   // lvl2 row-synth: [p][cc]=lo, [p][22+cc]=hi
    __shared__ float AR[35][36];   // a1r patch rows jr0..jr0+34, cols jc0..jc0+34
    __shared__ float LH[64][71];   // idwt1 row-synth

    int tid = threadIdx.x;
    float th2_h = 0.2f * (1.5f * __uint_as_float(mx2h[m]));
    float th2_v = 0.2f * (1.5f * __uint_as_float(mx2v[m]));
    float th2_d = 0.2f * (1.5f * __uint_as_float(mx2d[m]));
    float th1_h = 0.2f * (1.5f * __uint_as_float(mx1h[m]));
    float th1_v = 0.2f * (1.5f * __uint_as_float(mx1v[m]));
    float th1_d = 0.2f * (1.5f * __uint_as_float(mx1d[m]));
    const float* a2m = a2 + (size_t)m * n2 * ld2;
    const float* h2m = h2 + (size_t)m * n2 * ld2;
    const float* v2m = v2 + (size_t)m * n2 * ld2;
    const float* d2m = d2 + (size_t)m * n2 * ld2;
    const float* h1m = h1 + (size_t)m * n1 * ld1;
    const float* v1m = v1 + (size_t)m * n1 * ld1;
    const float* d1m = d1 + (size_t)m * n1 * ld1;

    // ---- phase 1a loads (issued FIRST so 1a's wait leaves hvd in flight)
    int g2 = tid / 21, cc = tid % 21;        // 189 tasks: g2 0..8
    bool act1a = (tid < 189);
    float A2r[5], H2r[5], V2r[5], D2r[5];
    if (act1a) {
        int c2 = q0c + cc; if (c2 > n2 - 1) c2 = n2 - 1;
#pragma unroll
        for (int rl = 0; rl < 5; ++rl) {
            int j2 = q0r + 2 * g2 + rl; if (j2 > n2 - 1) j2 = n2 - 1;
            size_t o = (size_t)j2 * ld2 + c2;
            A2r[rl] = a2m[o]; H2r[rl] = h2m[o];
            V2r[rl] = v2m[o]; D2r[rl] = d2m[o];
        }
    }

    // ---- phase 0: hoist this thread's h1/v1/d1 rows (used in phase 2a).
    int gA = tid / 35, jcA = tid % 35;       // tid<256 -> gA<=7
    int jcg = jc0 + jcA; if (jcg > n1 - 1) jcg = n1 - 1;
    int baseA = jr0 + 4 * gA;
    float Hg[7], Vg[7], Dg[7];
#pragma unroll
    for (int rr = 0; rr < 7; ++rr) {
        int jr = baseA + rr; if (jr > n1 - 1) jr = n1 - 1;
        size_t o = (size_t)jr * ld1 + jcg;
        Hg[rr] = h1m[o]; Vg[rr] = v1m[o]; Dg[rr] = d1m[o];
    }

    // ---- phase 1a compute: lvl2 synth along rows -> AH
    if (act1a) {
#pragma unroll
        for (int rl = 0; rl < 5; ++rl) {
            H2r[rl] = soft_enh(H2r[rl], th2_h);
            V2r[rl] = soft_enh(V2r[rl], th2_v);
            D2r[rl] = soft_enh(D2r[rl], th2_d);
        }
        float alo[4], ahi[4];
#pragma unroll
        for (int k = 0; k < 4; ++k) { alo[k] = 0.f; ahi[k] = 0.f; }
#pragma unroll
        for (int rl = 0; rl < 5; ++rl) {
#pragma unroll
            for (int t = 0; t < 8; ++t) {
                int k = 2 * rl + t - 6;
                if (k >= 0 && k < 4) {
                    alo[k] = fmaf(REC_LO[t], A2r[rl], fmaf(REC_HI[t], H2r[rl], alo[k]));
                    ahi[k] = fmaf(REC_LO[t], V2r[rl], fmaf(REC_HI[t], D2r[rl], ahi[k]));
                }
            }
        }
#pragma unroll
        for (int k = 0; k < 4; ++k) {
            int p = 4 * g2 + k;
            if (p < 35) { AH[p][cc] = alo[k]; AH[p][22 + cc] = ahi[k]; }
        }
    }
    __syncthreads();

    // ---- phase 1b: lvl2 synth along cols -> AR (1225 outputs)
    for (int e = tid; e < 1225; e += 256) {
        int p = e / 35, cl = e % 35;
        int t0 = cl & 1;
        float acc = 0.f;
#pragma unroll
        for (int s = 0; s < 4; ++s) {
            int t = t0 + 2 * s;
            int c = (cl + 6 - t) >> 1;
            acc = fmaf(REC_LO[t], AH[p][c], acc);
            acc = fmaf(REC_HI[t], AH[p][22 + c], acc);
        }
        AR[p][cl] = acc;
    }
    __syncthreads();

    // ---- phase 2a: idwt1 synth along rows -> LH (280 tasks)
    {   // round 1: task tid (hoisted hvd regs, a1r from LDS)
        float Ar[7], Hs[7], Vs[7], Ds[7];
#pragma unroll
        for (int rr = 0; rr < 7; ++rr) {
            Ar[rr] = AR[4 * gA + rr][jcA];
            Hs[rr] = soft_enh(Hg[rr], th1_h);
            Vs[rr] = soft_enh(Vg[rr], th1_v);
            Ds[rr] = soft_enh(Dg[rr], th1_d);
        }
#pragma unroll
        for (int pass = 0; pass < 2; ++pass) {
            int P = 2 * gA + pass;
            float acc_lo[4], acc_hi[4];
#pragma unroll
            for (int k = 0; k < 4; ++k) { acc_lo[k] = 0.f; acc_hi[k] = 0.f; }
#pragma unroll
            for (int rl = 0; rl < 5; ++rl) {
                int rr = 2 * pass + rl;
                float av = Ar[rr], hv = Hs[rr], vv = Vs[rr], dv = Ds[rr];
#pragma unroll
                for (int t = 0; t < 8; ++t) {
                    int k = 2 * rl + t - 6;
                    if (k >= 0 && k < 4) {
                        acc_lo[k] = fmaf(REC_LO[t], av, fmaf(REC_HI[t], hv, acc_lo[k]));
                        acc_hi[k] = fmaf(REC_LO[t], vv, fmaf(REC_HI[t], dv, acc_hi[k]));
                    }
                }
            }
#pragma unroll
            for (int k = 0; k < 4; ++k) {
                LH[4 * P + k][jcA] = acc_lo[k];
                LH[4 * P + k][35 + jcA] = acc_hi[k];
            }
        }
    }
    if (tid < 24) {  // round 2: tasks 256..279 (gB==7)
        int tk = tid + 256;
        int gB = tk / 35, jcB = tk % 35;
        int jcgB = jc0 + jcB; if (jcgB > n1 - 1) jcgB = n1 - 1;
        int baseB = jr0 + 4 * gB;
        float Ar[7], Hs[7], Vs[7], Ds[7];
#pragma unroll
        for (int rr = 0; rr < 7; ++rr) {
            int jr = baseB + rr; if (jr > n1 - 1) jr = n1 - 1;
            size_t o = (size_t)jr * ld1 + jcgB;
            Ar[rr] = AR[4 * gB + rr][jcB];
            Hs[rr] = soft_enh(h1m[o], th1_h);
            Vs[rr] = soft_enh(v1m[o], th1_v);
            Ds[rr] = soft_enh(d1m[o], th1_d);
        }
#pragma unroll
        for (int pass = 0; pass < 2; ++pass) {
            int P = 2 * gB + pass;
            float acc_lo[4], acc_hi[4];
#pragma unroll
            for (int k = 0; k < 4; ++k) { acc_lo[k] = 0.f; acc_hi[k] = 0.f; }
#pragma unroll
            for (int rl = 0; rl < 5; ++rl) {
                int rr = 2 * pass + rl;
                float av = Ar[rr], hv = Hs[rr], vv = Vs[rr], dv = Ds[rr];
#pragma unroll
                for (int t = 0; t < 8; ++t) {
                    int k = 2 * rl + t - 6;
                    if (k >= 0 && k < 4) {
                        acc_lo[k] = fmaf(REC_LO[t], av, fmaf(REC_HI[t], hv, acc_lo[k]));
                        acc_hi[k] = fmaf(REC_LO[t], vv, fmaf(REC_HI[t], dv, acc_hi[k]));
                    }
                }
            }
#pragma unroll
            for (int k = 0; k < 4; ++k) {
                LH[4 * P + k][jcB] = acc_lo[k];
                LH[4 * P + k][35 + jcB] = acc_hi[k];
            }
        }
    }
    __syncthreads();

    // ---- phase 2b: idwt1 synth along cols -> out tile (coalesced stores)
    for (int e = tid; e < TO * TO; e += 256) {
        int il = e >> 6, ul = e & 63;
        int t0 = ul & 1;
        float acc = 0.f;
#pragma unroll
        for (int s = 0; s < 4; ++s) {
            int t = t0 + 2 * s;
            int c = (ul + 6 - t) >> 1;
            acc = fmaf(REC_LO[t], LH[il][c], acc);
            acc = fmaf(REC_HI[t], LH[il][35 + c], acc);
        }
        int gi = i0 + il, gu = u0 + ul;
        if (gi < Ho && gu < Ho)
            out[((size_t)m * Ho + gi) * Ho + gu] = acc;
    }
}

extern "C" void kernel_launch(void* const* d_in, const int* in_sizes, int n_in,
                              void* d_out, int out_size, void* d_ws, size_t ws_size,
                              hipStream_t stream) {
    const float* x = (const float*)d_in[0];
    float* out = (float*)d_out;
    float* ws = (float*)d_ws;

    const int M = 96, S1 = 510, N1 = 258, N2 = 132;
    const int LD1 = 288, LD2 = 160;          // 128B-aligned band row strides
    const long P1 = (long)M * N1 * LD1;      // padded plane totals
    const long P2 = (long)M * N2 * LD2;

    float* aa1 = ws;
    float* h1  = aa1 + P1;
    float* v1  = h1 + P1;
    float* d1  = v1 + P1;
    float* a2  = d1 + P1;
    float* h2  = a2 + P2;
    float* v2  = h2 + P2;
    float* d2  = v2 + P2;
    unsigned* th = (unsigned*)(d2 + P2);     // 6*96 uints

    long need = 4 * P1 + 4 * P2 + 576;       // 36.6M floats = 146.6 MB
    if (ws_size < (size_t)need * sizeof(float)) return;

    unsigned *th_h1 = th, *th_v1 = th + 96, *th_d1 = th + 192;
    unsigned *th_h2 = th + 288, *th_v2 = th + 384, *th_d2 = th + 480;

    hipMemsetAsync(th, 0, 576 * sizeof(unsigned), stream);

    // Level 1 decomposition: x(510, ld 510) -> bands(258, ld 288). 9x9 tiles.
    fused_dwt2_k<<<9 * 9 * M, 256, 0, stream>>>(x, S1, S1, N1, LD1, 9,
                                                aa1, h1, v1, d1,
                                                th_h1, th_v1, th_d1);
    // Level 2 decomposition: aa1(258, ld 288) -> bands(132, ld 160). 5x5 tiles.
    fused_dwt2_k<<<5 * 5 * M, 256, 0, stream>>>(aa1, N1, LD1, N2, LD2, 5,
                                                a2, h2, v2, d2,
                                                th_h2, th_v2, th_d2);
    // Fused reconstruction: lvl2 bands + lvl1 details -> out(510). 8x8 tiles.
    fused_irec_k<<<8 * 8 * M, 256, 0, stream>>>(a2, h2, v2, d2, h1, v1, d1,
                                                th_h2, th_v2, th_d2,
                                                th_h1, th_v1, th_d1,
                                                N2, LD2, N1, LD1, S1, 8, out);
}